// Round 1
// baseline (395.219 us; speedup 1.0000x reference)
//
#include <hip/hip_runtime.h>
#include <math.h>

// Problem constants (from reference)
#define BB 4
#define SS 4096
#define HH 2048
#define EE 64
#define TOPK 8
#define NT (BB*SS)      // 16384 tokens
#define BT 64           // tokens per workgroup
#define KC 32           // K chunk size
#define NC (HH/KC)      // 64 chunks
#define LDH 36          // LDS row stride (floats) for hidden tile: 2-way bank conflict (free)

// One WG: 256 threads, 64 tokens x 64 experts, 4x4 register tile per thread.
__global__ __launch_bounds__(256, 1) void router_kernel(
    const float* __restrict__ x,      // [NT, H]
    const float* __restrict__ w,      // [E, H]
    float* __restrict__ out_logits,   // [NT, E]
    float* __restrict__ out_wts,      // [NT, 8]
    float* __restrict__ out_idx)      // [NT, 8] (indices stored as float)
{
    __shared__ float sh[2][BT * LDH];       // hidden tile, padded rows
    __shared__ float sw[2][EE * KC];        // gate_w tile, XOR-swizzled float4 columns
    __shared__ float slog[BT * (EE + 1)];   // logits tile for top-k, pad +1

    const int t  = threadIdx.x;
    const int tx = t & 15;          // expert group: experts 4*tx .. 4*tx+3
    const int ty = t >> 4;          // token group:  tokens  4*ty .. 4*ty+3
    const int tok0 = blockIdx.x * BT;

    float acc[4][4];
#pragma unroll
    for (int i = 0; i < 4; ++i)
#pragma unroll
        for (int j = 0; j < 4; ++j) acc[i][j] = 0.f;

    float4 ph[2], pw[2];

    // ---- prologue: global load chunk 0 into registers ----
#pragma unroll
    for (int r = 0; r < 2; ++r) {
        const int q   = t + r * 256;      // 0..511 over the 64x8 float4 tile
        const int row = q >> 3;           // token row / expert row
        const int c4  = q & 7;            // float4 column within chunk
        ph[r] = *(const float4*)(x + (size_t)(tok0 + row) * HH + c4 * 4);
        pw[r] = *(const float4*)(w + (size_t)row * HH + c4 * 4);
    }
    // store chunk 0 to LDS buf 0
#pragma unroll
    for (int r = 0; r < 2; ++r) {
        const int q   = t + r * 256;
        const int row = q >> 3;
        const int c4  = q & 7;
        *(float4*)&sh[0][row * LDH + c4 * 4] = ph[r];
        const int c4w = c4 ^ ((row >> 2) & 7);          // swizzle by expert>>2
        *(float4*)&sw[0][row * KC + c4w * 4] = pw[r];
    }
    __syncthreads();

    // ---- main K loop, double buffered ----
    for (int c = 0; c < NC; ++c) {
        const int buf = c & 1;

        if (c + 1 < NC) {
            const int k0 = (c + 1) * KC;
#pragma unroll
            for (int r = 0; r < 2; ++r) {
                const int q   = t + r * 256;
                const int row = q >> 3;
                const int c4  = q & 7;
                ph[r] = *(const float4*)(x + (size_t)(tok0 + row) * HH + k0 + c4 * 4);
                pw[r] = *(const float4*)(w + (size_t)row * HH + k0 + c4 * 4);
            }
        }

        // compute this chunk from LDS
#pragma unroll
        for (int kk = 0; kk < KC; kk += 4) {
            float4 ha[4], wb[4];
#pragma unroll
            for (int i = 0; i < 4; ++i)
                ha[i] = *(const float4*)&sh[buf][(4 * ty + i) * LDH + kk];
            const int c4w = (kk >> 2) ^ (tx & 7);
#pragma unroll
            for (int j = 0; j < 4; ++j)
                wb[j] = *(const float4*)&sw[buf][(4 * tx + j) * KC + c4w * 4];
#pragma unroll
            for (int i = 0; i < 4; ++i)
#pragma unroll
                for (int j = 0; j < 4; ++j) {
                    acc[i][j] = fmaf(ha[i].x, wb[j].x, acc[i][j]);
                    acc[i][j] = fmaf(ha[i].y, wb[j].y, acc[i][j]);
                    acc[i][j] = fmaf(ha[i].z, wb[j].z, acc[i][j]);
                    acc[i][j] = fmaf(ha[i].w, wb[j].w, acc[i][j]);
                }
        }

        if (c + 1 < NC) {
            const int nbuf = (c + 1) & 1;
#pragma unroll
            for (int r = 0; r < 2; ++r) {
                const int q   = t + r * 256;
                const int row = q >> 3;
                const int c4  = q & 7;
                *(float4*)&sh[nbuf][row * LDH + c4 * 4] = ph[r];
                const int c4w = c4 ^ ((row >> 2) & 7);
                *(float4*)&sw[nbuf][row * KC + c4w * 4] = pw[r];
            }
        }
        __syncthreads();
    }

    // ---- epilogue: write logits (global + LDS for top-k) ----
#pragma unroll
    for (int i = 0; i < 4; ++i) {
        float4 v;
        v.x = acc[i][0]; v.y = acc[i][1]; v.z = acc[i][2]; v.w = acc[i][3];
        *(float4*)(out_logits + (size_t)(tok0 + 4 * ty + i) * EE + 4 * tx) = v;
        const int base = (4 * ty + i) * (EE + 1) + 4 * tx;
        slog[base + 0] = acc[i][0];
        slog[base + 1] = acc[i][1];
        slog[base + 2] = acc[i][2];
        slog[base + 3] = acc[i][3];
    }
    __syncthreads();

    // ---- top-8 + softmax: one lane per token (wave 0) ----
    if (t < BT) {
        float tv[TOPK];
        int   ti[TOPK];
#pragma unroll
        for (int p = 0; p < TOPK; ++p) { tv[p] = -INFINITY; ti[p] = 0; }

        for (int e = 0; e < EE; ++e) {
            const float v = slog[t * (EE + 1) + e];
            if (v > tv[TOPK - 1]) {
                tv[TOPK - 1] = v;
                ti[TOPK - 1] = e;
                // bubble up; strict > keeps lowest-index-first on ties (lax.top_k)
#pragma unroll
                for (int p = TOPK - 1; p > 0; --p) {
                    if (tv[p] > tv[p - 1]) {
                        float fv = tv[p]; tv[p] = tv[p - 1]; tv[p - 1] = fv;
                        int   fi = ti[p]; ti[p] = ti[p - 1]; ti[p - 1] = fi;
                    }
                }
            }
        }

        const float m = tv[0];
        float ew[TOPK];
        float s = 0.f;
#pragma unroll
        for (int p = 0; p < TOPK; ++p) { ew[p] = expf(tv[p] - m); s += ew[p]; }
        const float inv = 1.f / s;

        const size_t tok = (size_t)(tok0 + t);
        float4 w0, w1, i0, i1;
        w0.x = ew[0] * inv; w0.y = ew[1] * inv; w0.z = ew[2] * inv; w0.w = ew[3] * inv;
        w1.x = ew[4] * inv; w1.y = ew[5] * inv; w1.z = ew[6] * inv; w1.w = ew[7] * inv;
        i0.x = (float)ti[0]; i0.y = (float)ti[1]; i0.z = (float)ti[2]; i0.w = (float)ti[3];
        i1.x = (float)ti[4]; i1.y = (float)ti[5]; i1.z = (float)ti[6]; i1.w = (float)ti[7];
        *(float4*)(out_wts + tok * TOPK)     = w0;
        *(float4*)(out_wts + tok * TOPK + 4) = w1;
        *(float4*)(out_idx + tok * TOPK)     = i0;
        *(float4*)(out_idx + tok * TOPK + 4) = i1;
    }
}

extern "C" void kernel_launch(void* const* d_in, const int* in_sizes, int n_in,
                              void* d_out, int out_size, void* d_ws, size_t ws_size,
                              hipStream_t stream) {
    const float* x = (const float*)d_in[0];   // hidden_states [4,4096,2048]
    const float* w = (const float*)d_in[1];   // gate_w [64,2048]
    float* out        = (float*)d_out;
    float* out_logits = out;                               // 16384*64
    float* out_wts    = out + (size_t)NT * EE;             // 16384*8
    float* out_idx    = out_wts + (size_t)NT * TOPK;       // 16384*8

    dim3 grid(NT / BT), block(256);
    hipLaunchKernelGGL(router_kernel, grid, block, 0, stream,
                       x, w, out_logits, out_wts, out_idx);
}